// Round 1
// baseline (652.489 us; speedup 1.0000x reference)
//
#include <hip/hip_runtime.h>

// Problem constants: B=8, S=16, E=2048, H=16, D=128, Tc=4096 (cache), T=4112
#define E_DIM 2048
#define H_NUM 16
#define D_DIM 128
#define S_NEW 16
#define TC 4096

typedef float floatx4 __attribute__((ext_vector_type(4)));
typedef short short8 __attribute__((ext_vector_type(8)));

// scale * log2(e) : scores tracked raw, exp2-based softmax
#define CC (0.08838834764831845f * 1.4426950408889634f)

__device__ __forceinline__ short f2bf(float f) {
  union { float f; unsigned u; } v; v.f = f;
  unsigned u = v.u;
  unsigned r = (u + 0x7FFFu + ((u >> 16) & 1u)) >> 16;  // RNE
  return (short)r;
}
__device__ __forceinline__ float bf2f(unsigned short s) {
  union { unsigned u; float f; } v; v.u = ((unsigned)s) << 16; return v.f;
}
__device__ __forceinline__ short8 cvt8(float4 a, float4 b) {
  short8 r;
  r[0]=f2bf(a.x); r[1]=f2bf(a.y); r[2]=f2bf(a.z); r[3]=f2bf(a.w);
  r[4]=f2bf(b.x); r[5]=f2bf(b.y); r[6]=f2bf(b.z); r[7]=f2bf(b.w);
  return r;
}

// ---------------------------------------------------------------------------
// Kernel A: QKV projection. y[m][n] = sum_e X[m][e] * W[n][e] + b[n]
// m = b*16+s (128 rows), n = h*128+d (2048). 16x32 tile per wave (1 wave/block).
// grid: 3 weights * 8 mtiles * 64 ntiles = 1536 blocks x 64 threads.
// ---------------------------------------------------------------------------
__global__ __launch_bounds__(64) void qkv_kernel(
    const float* __restrict__ X,
    const float* __restrict__ Wq, const float* __restrict__ bq,
    const float* __restrict__ Wk, const float* __restrict__ bk,
    const float* __restrict__ Wv, const float* __restrict__ bv,
    unsigned short* __restrict__ q_ws,
    float* __restrict__ out_knew, float* __restrict__ out_vnew)
{
  int bid = blockIdx.x;
  int w   = bid >> 9;         // 0=q 1=k 2=v
  int rem = bid & 511;
  int mt  = rem >> 6;         // 8 mtiles of 16
  int nt  = rem & 63;         // 64 ntiles of 32
  int m0 = mt * 16, n0 = nt * 32;
  const float* W    = (w == 0) ? Wq : (w == 1) ? Wk : Wv;
  const float* bias = (w == 0) ? bq : (w == 1) ? bk : bv;

  int l = threadIdx.x;
  int lm = l & 15, lq = l >> 4;

  const float* xrow  = X + (m0 + lm) * E_DIM + lq * 8;
  const float* wrow0 = W + (n0 + lm) * E_DIM + lq * 8;
  const float* wrow1 = wrow0 + 16 * E_DIM;

  floatx4 acc0 = {0.f,0.f,0.f,0.f}, acc1 = {0.f,0.f,0.f,0.f};
  #pragma unroll 2
  for (int k0 = 0; k0 < E_DIM; k0 += 32) {
    const float4* xa = (const float4*)(xrow + k0);
    const float4* b0 = (const float4*)(wrow0 + k0);
    const float4* b1 = (const float4*)(wrow1 + k0);
    short8 a  = cvt8(xa[0], xa[1]);
    short8 f0 = cvt8(b0[0], b0[1]);
    short8 f1 = cvt8(b1[0], b1[1]);
    acc0 = __builtin_amdgcn_mfma_f32_16x16x32_bf16(a, f0, acc0, 0, 0, 0);
    acc1 = __builtin_amdgcn_mfma_f32_16x16x32_bf16(a, f1, acc1, 0, 0, 0);
  }
  // epilogue: C layout col=lane&15 (n), row=(lane>>4)*4+r (m)
  #pragma unroll
  for (int f = 0; f < 2; ++f) {
    floatx4 acc = f ? acc1 : acc0;
    int n = n0 + f * 16 + lm;
    float bb = bias[n];
    int h = n >> 7, d = n & 127;
    #pragma unroll
    for (int r = 0; r < 4; ++r) {
      int m = m0 + lq * 4 + r;
      int b = m >> 4, s = m & 15;
      float val = acc[r] + bb;
      long idx = (((long)(b * H_NUM + h) * S_NEW + s) * D_DIM + d);
      if (w == 0)      q_ws[idx]     = (unsigned short)f2bf(val);
      else if (w == 1) out_knew[idx] = val;
      else             out_vnew[idx] = val;
    }
  }
}

// ---------------------------------------------------------------------------
// Kernel B: flash attention over the 4096 cached tokens, split-T.
// grid: (b*h)*8 chunks = 1024 blocks x 256 threads (4 waves).
// Each wave: 128 tokens, online softmax, partial (m,l,O). Block merges 4 waves
// -> one partial per chunk into O_part / ml_part.
// ---------------------------------------------------------------------------
__global__ __launch_bounds__(256) void attn_kernel(
    const float* __restrict__ Kc, const float* __restrict__ Vc,
    const unsigned short* __restrict__ q_ws,
    float* __restrict__ O_part, float* __restrict__ ml_part)
{
  __shared__ float lds_o[4][16][128];
  __shared__ float lds_m[4][16];
  __shared__ float lds_l[4][16];
  __shared__ __align__(16) unsigned short p_buf[4][16 * 40];  // pitch 40 shorts (80B, 16B-aligned rows)

  int bh = blockIdx.x >> 3;
  int c  = blockIdx.x & 7;
  int w  = threadIdx.x >> 6;
  int l  = threadIdx.x & 63;
  int lm = l & 15, lq = l >> 4;

  // Q A-frags (4 frags cover D=128): A[m=lane&15][k=(lane>>4)*8+j]
  short8 qf[4];
  const unsigned short* qrow = q_ws + ((long)bh * S_NEW + lm) * D_DIM + lq * 8;
  #pragma unroll
  for (int i = 0; i < 4; ++i) qf[i] = *(const short8*)(qrow + i * 32);

  const float* Kbase = Kc + (long)bh * TC * D_DIM;
  const float* Vbase = Vc + (long)bh * TC * D_DIM;
  int tw = c * 512 + w * 128;

  floatx4 o[8];
  #pragma unroll
  for (int f = 0; f < 8; ++f) o[f] = (floatx4){0.f,0.f,0.f,0.f};
  float mrun[4] = {-1e30f,-1e30f,-1e30f,-1e30f};
  float lrun[4] = {0.f,0.f,0.f,0.f};

  unsigned short* pw = &p_buf[w][0];

  for (int it = 0; it < 4; ++it) {
    int t0 = tw + it * 32;
    // ---- QK^T for 32 tokens: scores s0 (tokens t0..t0+15), s1 (+16..31)
    floatx4 s0 = {0.f,0.f,0.f,0.f}, s1 = {0.f,0.f,0.f,0.f};
    const float* k0p = Kbase + (long)(t0 + lm) * D_DIM + lq * 8;
    const float* k1p = k0p + 16 * D_DIM;
    #pragma unroll
    for (int i = 0; i < 4; ++i) {
      const float4* ka = (const float4*)(k0p + i * 32);
      const float4* kb = (const float4*)(k1p + i * 32);
      short8 kf0 = cvt8(ka[0], ka[1]);
      short8 kf1 = cvt8(kb[0], kb[1]);
      s0 = __builtin_amdgcn_mfma_f32_16x16x32_bf16(qf[i], kf0, s0, 0, 0, 0);
      s1 = __builtin_amdgcn_mfma_f32_16x16x32_bf16(qf[i], kf1, s1, 0, 0, 0);
    }
    // ---- online softmax. C layout: row s=(lq*4+r), col t=lm (per 16-tile)
    float mx[4];
    #pragma unroll
    for (int r = 0; r < 4; ++r) mx[r] = fmaxf(s0[r], s1[r]);
    #pragma unroll
    for (int off = 1; off < 16; off <<= 1) {
      #pragma unroll
      for (int r = 0; r < 4; ++r) mx[r] = fmaxf(mx[r], __shfl_xor(mx[r], off));
    }
    // WAR fence: prior iter's p_buf reads done before overwrite
    asm volatile("s_waitcnt lgkmcnt(0)" ::: "memory");
    float alpha[4], psum[4];
    #pragma unroll
    for (int r = 0; r < 4; ++r) {
      float mn = fmaxf(mrun[r], mx[r]);
      alpha[r] = exp2f((mrun[r] - mn) * CC);
      float p0 = exp2f((s0[r] - mn) * CC);
      float p1 = exp2f((s1[r] - mn) * CC);
      mrun[r] = mn;
      int row = lq * 4 + r;
      pw[row * 40 + lm]      = (unsigned short)f2bf(p0);
      pw[row * 40 + 16 + lm] = (unsigned short)f2bf(p1);
      psum[r] = p0 + p1;
    }
    #pragma unroll
    for (int off = 1; off < 16; off <<= 1) {
      #pragma unroll
      for (int r = 0; r < 4; ++r) psum[r] += __shfl_xor(psum[r], off);
    }
    #pragma unroll
    for (int r = 0; r < 4; ++r) {
      lrun[r] = lrun[r] * alpha[r] + psum[r];
      #pragma unroll
      for (int f = 0; f < 8; ++f) o[f][r] *= alpha[r];
    }
    // RAW fence: p writes visible before A-frag read
    asm volatile("s_waitcnt lgkmcnt(0)" ::: "memory");
    short8 pf = *(const short8*)(pw + lm * 40 + lq * 8);
    // ---- PV: B[k=t][n=d], lane elem j = V[t0+lq*8+j][f*16+lm]
    const float* vp = Vbase + (long)(t0 + lq * 8) * D_DIM + lm;
    #pragma unroll
    for (int f = 0; f < 8; ++f) {
      short8 vf;
      #pragma unroll
      for (int j = 0; j < 8; ++j) vf[j] = f2bf(vp[(long)j * D_DIM + f * 16]);
      o[f] = __builtin_amdgcn_mfma_f32_16x16x32_bf16(pf, vf, o[f], 0, 0, 0);
    }
  }

  // ---- merge 4 wave partials within the block
  #pragma unroll
  for (int f = 0; f < 8; ++f)
    #pragma unroll
    for (int r = 0; r < 4; ++r)
      lds_o[w][lq * 4 + r][f * 16 + lm] = o[f][r];
  if (lm == 0) {
    #pragma unroll
    for (int r = 0; r < 4; ++r) {
      lds_m[w][lq * 4 + r] = mrun[r];
      lds_l[w][lq * 4 + r] = lrun[r];
    }
  }
  __syncthreads();

  int tid = threadIdx.x;
  int s = tid >> 4, d0 = (tid & 15) * 8;
  float M = -1e30f;
  #pragma unroll
  for (int ww = 0; ww < 4; ++ww) M = fmaxf(M, lds_m[ww][s]);
  float wf[4]; float L = 0.f;
  #pragma unroll
  for (int ww = 0; ww < 4; ++ww) {
    wf[ww] = exp2f((lds_m[ww][s] - M) * CC);
    L += lds_l[ww][s] * wf[ww];
  }
  float* op = O_part + ((((long)bh * 8 + c) * S_NEW + s) * D_DIM) + d0;
  #pragma unroll
  for (int dd = 0; dd < 8; ++dd) {
    float acc = 0.f;
    #pragma unroll
    for (int ww = 0; ww < 4; ++ww) acc += wf[ww] * lds_o[ww][s][d0 + dd];
    op[dd] = acc;
  }
  if ((tid & 15) == 0) {
    long mi = (((long)bh * 8 + c) * S_NEW + s) * 2;
    ml_part[mi]     = M;
    ml_part[mi + 1] = L;
  }
}

// ---------------------------------------------------------------------------
// Kernel C: combine 8 chunk partials + 16 causally-masked new tokens,
// normalize, write ctx (B,S,E) bf16. grid: 128 blocks (b*h) x 256 threads.
// ---------------------------------------------------------------------------
__global__ __launch_bounds__(256) void combine_kernel(
    const float* __restrict__ O_part, const float* __restrict__ ml_part,
    const unsigned short* __restrict__ q_ws,
    const float* __restrict__ k_new, const float* __restrict__ v_new,
    unsigned short* __restrict__ ctx)
{
  __shared__ float sc[16][17];
  int bh = blockIdx.x;
  int b = bh >> 4, h = bh & 15;
  int tid = threadIdx.x;
  int s = tid >> 4, j = tid & 15;

  // phase 1: raw new-token scores sc[s][j] = q[s].k_new[j]
  {
    const unsigned short* qp = q_ws + ((long)bh * S_NEW + s) * D_DIM;
    const float* kp = k_new + ((long)bh * S_NEW + j) * D_DIM;
    float acc = 0.f;
    for (int d = 0; d < D_DIM; ++d) acc += bf2f(qp[d]) * kp[d];
    sc[s][j] = acc;
  }
  __syncthreads();

  // phase 2: global max / denom per row s (redundant across the 16 threads of a row)
  float mc[8], lc[8];
  #pragma unroll
  for (int c2 = 0; c2 < 8; ++c2) {
    long mi = (((long)bh * 8 + c2) * S_NEW + s) * 2;
    mc[c2] = ml_part[mi];
    lc[c2] = ml_part[mi + 1];
  }
  float M = -1e30f;
  #pragma unroll
  for (int c2 = 0; c2 < 8; ++c2) M = fmaxf(M, mc[c2]);
  for (int jj = 0; jj <= s; ++jj) M = fmaxf(M, sc[s][jj]);
  float L = 0.f; float wfc[8];
  #pragma unroll
  for (int c2 = 0; c2 < 8; ++c2) { wfc[c2] = exp2f((mc[c2] - M) * CC); L += lc[c2] * wfc[c2]; }
  float p[16];
  #pragma unroll
  for (int jj = 0; jj < 16; ++jj) {
    p[jj] = (jj <= s) ? exp2f((sc[s][jj] - M) * CC) : 0.f;
    L += p[jj];
  }
  float Linv = 1.f / L;

  // phase 3: normalized output, 8 d-elements per thread
  int d0 = (tid & 15) * 8;
  float accv[8];
  #pragma unroll
  for (int dd = 0; dd < 8; ++dd) accv[dd] = 0.f;
  for (int c2 = 0; c2 < 8; ++c2) {
    const float* op = O_part + ((((long)bh * 8 + c2) * S_NEW + s) * D_DIM) + d0;
    float wv = wfc[c2];
    #pragma unroll
    for (int dd = 0; dd < 8; ++dd) accv[dd] += wv * op[dd];
  }
  for (int jj = 0; jj <= s; ++jj) {
    const float* vp = v_new + ((long)bh * S_NEW + jj) * D_DIM + d0;
    float pv = p[jj];
    #pragma unroll
    for (int dd = 0; dd < 8; ++dd) accv[dd] += pv * vp[dd];
  }
  unsigned short* cp = ctx + ((long)(b * S_NEW + s)) * E_DIM + h * D_DIM + d0;
  #pragma unroll
  for (int dd = 0; dd < 8; ++dd) cp[dd] = (unsigned short)f2bf(accv[dd] * Linv);
}

// ---------------------------------------------------------------------------
// Kernel D: output projection. out[m][n] = sum_e ctx[m][e]*Wo[n][e] + bo[n]
// grid: 8 mtiles * 64 ntiles = 512 blocks x 64 threads.
// ---------------------------------------------------------------------------
__global__ __launch_bounds__(64) void oproj_kernel(
    const unsigned short* __restrict__ ctx, const float* __restrict__ Wo,
    const float* __restrict__ bo, float* __restrict__ out)
{
  int bid = blockIdx.x;
  int mt = bid >> 6, nt = bid & 63;
  int m0 = mt * 16, n0 = nt * 32;
  int l = threadIdx.x, lm = l & 15, lq = l >> 4;

  const unsigned short* arow = ctx + (m0 + lm) * E_DIM + lq * 8;
  const float* w0 = Wo + (n0 + lm) * E_DIM + lq * 8;
  const float* w1 = w0 + 16 * E_DIM;

  floatx4 acc0 = {0.f,0.f,0.f,0.f}, acc1 = {0.f,0.f,0.f,0.f};
  #pragma unroll 2
  for (int k0 = 0; k0 < E_DIM; k0 += 32) {
    short8 a = *(const short8*)(arow + k0);
    const float4* b0 = (const float4*)(w0 + k0);
    const float4* b1 = (const float4*)(w1 + k0);
    short8 f0 = cvt8(b0[0], b0[1]);
    short8 f1 = cvt8(b1[0], b1[1]);
    acc0 = __builtin_amdgcn_mfma_f32_16x16x32_bf16(a, f0, acc0, 0, 0, 0);
    acc1 = __builtin_amdgcn_mfma_f32_16x16x32_bf16(a, f1, acc1, 0, 0, 0);
  }
  #pragma unroll
  for (int f = 0; f < 2; ++f) {
    floatx4 acc = f ? acc1 : acc0;
    int n = n0 + f * 16 + lm;
    float bb = bo[n];
    #pragma unroll
    for (int r = 0; r < 4; ++r) {
      int m = m0 + lq * 4 + r;
      out[(long)m * E_DIM + n] = acc[r] + bb;
    }
  }
}

extern "C" void kernel_launch(void* const* d_in, const int* in_sizes, int n_in,
                              void* d_out, int out_size, void* d_ws, size_t ws_size,
                              hipStream_t stream) {
  const float* emb     = (const float*)d_in[0];
  const float* k_cache = (const float*)d_in[1];
  const float* v_cache = (const float*)d_in[2];
  const float* Wq = (const float*)d_in[3];
  const float* bq = (const float*)d_in[4];
  const float* Wk = (const float*)d_in[5];
  const float* bk = (const float*)d_in[6];
  const float* Wv = (const float*)d_in[7];
  const float* bv = (const float*)d_in[8];
  const float* Wo = (const float*)d_in[9];
  const float* bo = (const float*)d_in[10];

  float* out   = (float*)d_out;          // (8,16,2048)
  float* k_new = out + 262144;           // (8,16,16,128)
  float* v_new = out + 524288;           // (8,16,16,128)

  char* ws = (char*)d_ws;
  unsigned short* q_ws  = (unsigned short*)ws;                         // 512 KB bf16 (B,H,S,D)
  float* O_part         = (float*)(ws + 524288);                       // 8 MB (bh,8,16,128)
  float* ml_part        = (float*)(ws + 524288 + 8388608);             // 128 KB
  unsigned short* ctx   = (unsigned short*)(ws + 524288 + 8388608 + 131072); // 512 KB bf16 (B,S,E)

  qkv_kernel<<<1536, 64, 0, stream>>>(emb, Wq, bq, Wk, bk, Wv, bv, q_ws, k_new, v_new);
  attn_kernel<<<1024, 256, 0, stream>>>(k_cache, v_cache, q_ws, O_part, ml_part);
  combine_kernel<<<128, 256, 0, stream>>>(O_part, ml_part, q_ws, k_new, v_new, ctx);
  oproj_kernel<<<512, 64, 0, stream>>>(ctx, Wo, bo, out);
}